// Round 1
// baseline (209.686 us; speedup 1.0000x reference)
//
#include <hip/hip_runtime.h>
#include <stdint.h>

// ColBERT MaxSim on MI355X (gfx950).
// scores[b,c] = sum_n max_s dot(qs[b,n,:], ps[c,s,:])
// qs: (64, 32, 128) f32, ps: (64, 1024, 128) f32, out: (64, 64) f32.
//
// Strategy: cast inputs to bf16 (pre-pass into d_ws), then per (b,c) pair one
// 256-thread block (4 waves). MFMA 32x32x16 bf16 with A = P rows (M = doc
// tokens s), B = Q (N = 32 query tokens). C/D layout: col = lane&31 = query
// token, rows = s — so max-over-s is a per-lane max over the 16 acc regs,
// folded with shfl_xor(32), then cross-wave max in LDS, then sum over the 32
// query tokens.

typedef __bf16 bf16x8 __attribute__((ext_vector_type(8)));
typedef float floatx16 __attribute__((ext_vector_type(16)));

__device__ inline unsigned short f2bf(float f) {
  union { float f; uint32_t u; } x{f};
  uint32_t r = (x.u + 0x7FFFu + ((x.u >> 16) & 1u)) >> 16;  // RNE
  return (unsigned short)r;
}

__global__ __launch_bounds__(256) void cvt_kernel(const float* __restrict__ in,
                                                  ushort* __restrict__ out, int n4) {
  int i = blockIdx.x * 256 + threadIdx.x;
  if (i >= n4) return;
  float4 f = ((const float4*)in)[i];
  ushort4 o;
  o.x = f2bf(f.x); o.y = f2bf(f.y); o.z = f2bf(f.z); o.w = f2bf(f.w);
  ((ushort4*)out)[i] = o;
}

union FragU { uint4 u; bf16x8 v; };

__device__ inline bf16x8 load_frag_bf16(const ushort* p) {
  FragU f;
  f.u = *(const uint4*)p;  // 16 B = 8 bf16, aligned
  return f.v;
}

__device__ inline bf16x8 load_frag_f32(const float* p) {
  float4 a = *(const float4*)p;
  float4 b = *(const float4*)(p + 4);
  union { ushort s[8]; bf16x8 v; } r;
  r.s[0] = f2bf(a.x); r.s[1] = f2bf(a.y); r.s[2] = f2bf(a.z); r.s[3] = f2bf(a.w);
  r.s[4] = f2bf(b.x); r.s[5] = f2bf(b.y); r.s[6] = f2bf(b.z); r.s[7] = f2bf(b.w);
  return r.v;
}

template <bool PRECVT>
__global__ __launch_bounds__(256) void maxsim_kernel(const void* __restrict__ qs,
                                                     const void* __restrict__ ps,
                                                     float* __restrict__ out) {
  const int lane = threadIdx.x & 63;
  const int wave = threadIdx.x >> 6;
  const int b = blockIdx.x & 63;   // b fastest: 64 consecutive blocks share P_c (L2 locality)
  const int c = blockIdx.x >> 6;
  const int row = lane & 31;           // A: s row within tile; B: query token n
  const int koff = (lane >> 5) * 8;    // K half selector

  // Q fragments for all 8 K-steps (K=128 = 8 x 16), held in registers.
  // B-operand layout: B[n = lane&31][k = (lane>>5)*8 + j], j = 0..7 contiguous.
  bf16x8 qfrag[8];
#pragma unroll
  for (int k = 0; k < 8; ++k) {
    const int off = (b * 32 + row) * 128 + k * 16 + koff;
    qfrag[k] = PRECVT ? load_frag_bf16((const ushort*)qs + off)
                      : load_frag_f32((const float*)qs + off);
  }

  // Each wave covers s in [wave*256, wave*256+256): 8 tiles of 32 doc tokens.
  float vmax = -3.4e38f;
  const int pbase = (c * 1024 + wave * 256 + row) * 128 + koff;
  for (int t = 0; t < 8; ++t) {
    const int pt = pbase + t * 32 * 128;
    floatx16 acc = {0, 0, 0, 0, 0, 0, 0, 0, 0, 0, 0, 0, 0, 0, 0, 0};
#pragma unroll
    for (int k = 0; k < 8; ++k) {
      // A-operand layout: A[m = lane&31][k = (lane>>5)*8 + j]
      bf16x8 a = PRECVT ? load_frag_bf16((const ushort*)ps + pt + k * 16)
                        : load_frag_f32((const float*)ps + pt + k * 16);
      acc = __builtin_amdgcn_mfma_f32_32x32x16_bf16(a, qfrag[k], acc, 0, 0, 0);
    }
    // Running max over this tile's 16 s-rows (all same query token col).
#pragma unroll
    for (int i = 0; i < 16; ++i) vmax = fmaxf(vmax, acc[i]);
  }
  // Lane l and l^32 cover complementary row halves for the same col.
  vmax = fmaxf(vmax, __shfl_xor(vmax, 32, 64));

  // Cross-wave max, then sum over the 32 query tokens.
  __shared__ float red[4][32];
  if (lane < 32) red[wave][lane] = vmax;
  __syncthreads();
  if (threadIdx.x < 32) {
    const int n = threadIdx.x;
    float m = fmaxf(fmaxf(red[0][n], red[1][n]), fmaxf(red[2][n], red[3][n]));
#pragma unroll
    for (int o = 16; o > 0; o >>= 1) m += __shfl_xor(m, o, 32);
    if (n == 0) out[b * 64 + c] = m;
  }
}

extern "C" void kernel_launch(void* const* d_in, const int* in_sizes, int n_in,
                              void* d_out, int out_size, void* d_ws, size_t ws_size,
                              hipStream_t stream) {
  const float* qs = (const float*)d_in[0];
  const float* ps = (const float*)d_in[1];
  float* out = (float*)d_out;

  const size_t QS_N = 64u * 32u * 128u;     // 262144
  const size_t PS_N = 64u * 1024u * 128u;   // 8388608
  const size_t need = (QS_N + PS_N) * sizeof(ushort);  // 16.5 MiB

  if (ws_size >= need) {
    ushort* qsb = (ushort*)d_ws;
    ushort* psb = qsb + QS_N;
    cvt_kernel<<<(int)(QS_N / 4 / 256), 256, 0, stream>>>(qs, qsb, (int)(QS_N / 4));
    cvt_kernel<<<(int)(PS_N / 4 / 256), 256, 0, stream>>>(ps, psb, (int)(PS_N / 4));
    maxsim_kernel<true><<<dim3(64 * 64), dim3(256), 0, stream>>>(qsb, psb, out);
  } else {
    maxsim_kernel<false><<<dim3(64 * 64), dim3(256), 0, stream>>>(qs, ps, out);
  }
}

// Round 3
// 128.274 us; speedup vs baseline: 1.6347x; 1.6347x over previous
//
#include <hip/hip_runtime.h>
#include <stdint.h>

// ColBERT MaxSim on MI355X (gfx950), round 3.
// scores[b,c] = sum_n max_s dot(qs[b,n,:], ps[c,s,:])
// qs: (64, 32, 128) f32, ps: (64, 1024, 128) f32, out: (64, 64) f32.
//
// R1 (passed, 140 us): latency-bound, AI = 1 MFMA per A-load, MfmaUtil 9.7%.
// R2 (crashed): NB=4 + dbuf, but __launch_bounds__(256,2) forced a 256-VGPR
//   cap below the ~280-reg live set -> spill-to-scratch (suspected abort).
// R3: same NB=4 + register double-buffer, but b-major acc chains (one 16-reg
//   acc live), everything inlined, no forced VGPR cap (~230 regs, no spill).

typedef __bf16 bf16x8 __attribute__((ext_vector_type(8)));
typedef float floatx16 __attribute__((ext_vector_type(16)));

#define QS_N (64u * 32u * 128u)    // 262144
#define PS_N (64u * 1024u * 128u)  // 8388608

__device__ inline unsigned short f2bf(float f) {
  union { float f; uint32_t u; } x{f};
  uint32_t r = (x.u + 0x7FFFu + ((x.u >> 16) & 1u)) >> 16;  // RNE
  return (unsigned short)r;
}

// Fused cvt: first QS_N/4 float4s from qs, rest from ps; output contiguous so
// qsb = ws, psb = ws + QS_N. Explicit if/else (no speculative-load ambiguity).
__global__ __launch_bounds__(256) void cvt_kernel(const float* __restrict__ qs,
                                                  const float* __restrict__ ps,
                                                  ushort* __restrict__ outb) {
  const int nq4 = QS_N / 4;
  const int n4 = (QS_N + PS_N) / 4;
  int i = blockIdx.x * 256 + threadIdx.x;
  if (i >= n4) return;
  float4 f;
  if (i < nq4) {
    f = ((const float4*)qs)[i];
  } else {
    f = ((const float4*)ps)[i - nq4];
  }
  ushort4 o;
  o.x = f2bf(f.x); o.y = f2bf(f.y); o.z = f2bf(f.z); o.w = f2bf(f.w);
  ((ushort4*)outb)[i] = o;
}

union FragU { uint4 u; bf16x8 v; };

__device__ inline bf16x8 load_frag_bf16(const ushort* p) {
  FragU f;
  f.u = *(const uint4*)p;
  return f.v;
}

__device__ inline bf16x8 load_frag_f32(const float* p) {
  float4 a = *(const float4*)p;
  float4 b = *(const float4*)(p + 4);
  union { ushort s[8]; bf16x8 v; } r;
  r.s[0] = f2bf(a.x); r.s[1] = f2bf(a.y); r.s[2] = f2bf(a.z); r.s[3] = f2bf(a.w);
  r.s[4] = f2bf(b.x); r.s[5] = f2bf(b.y); r.s[6] = f2bf(b.z); r.s[7] = f2bf(b.w);
  return r.v;
}

template <bool PRECVT>
__device__ inline bf16x8 load_a(const void* p, int off) {
  return PRECVT ? load_frag_bf16((const ushort*)p + off)
                : load_frag_f32((const float*)p + off);
}

template <bool PRECVT>
__global__ __launch_bounds__(256) void maxsim_kernel(const void* __restrict__ qsv,
                                                     const void* __restrict__ psv,
                                                     float* __restrict__ out) {
  const int lane = threadIdx.x & 63;
  const int wave = threadIdx.x >> 6;
  const int bg = blockIdx.x & 15;  // 16 consecutive blocks share P_c (L2 locality)
  const int c = blockIdx.x >> 4;
  const int row = lane & 31;         // A: s-row in tile; B: query token n
  const int koff = (lane >> 5) * 8;  // K-half selector
  const int b0 = bg * 4;

  // Wave covers s in [wave*256, wave*256+256): 8 tiles of 32 doc tokens.
  const int pbase = (c * 1024 + wave * 256 + row) * 128 + koff;

  // Issue tile-0 A prefetch first (longest-latency loads go out first).
  bf16x8 a0[8], a1[8];
#pragma unroll
  for (int k = 0; k < 8; ++k) a0[k] = load_a<PRECVT>(psv, pbase + k * 16);

  // Q fragments for 4 query blocks x 8 K-steps, in registers (128 VGPRs).
  // B-operand layout: B[n = lane&31][k = (lane>>5)*8 + j].
  bf16x8 qf[4][8];
#pragma unroll
  for (int b = 0; b < 4; ++b)
#pragma unroll
    for (int k = 0; k < 8; ++k)
      qf[b][k] = load_a<PRECVT>(qsv, ((b0 + b) * 32 + row) * 128 + k * 16 + koff);

  float vmax[4];
#pragma unroll
  for (int b = 0; b < 4; ++b) vmax[b] = -3.4e38f;

#pragma unroll 1
  for (int t = 0; t < 8; t += 2) {
    // Prefetch tile t+1 into a1; compute tile t from a0 (b-major: 1 acc live).
#pragma unroll
    for (int k = 0; k < 8; ++k)
      a1[k] = load_a<PRECVT>(psv, pbase + (t + 1) * 4096 + k * 16);
#pragma unroll
    for (int b = 0; b < 4; ++b) {
      floatx16 acc = {0, 0, 0, 0, 0, 0, 0, 0, 0, 0, 0, 0, 0, 0, 0, 0};
#pragma unroll
      for (int k = 0; k < 8; ++k)
        acc = __builtin_amdgcn_mfma_f32_32x32x16_bf16(a0[k], qf[b][k], acc, 0, 0, 0);
      float m0 = fmaxf(fmaxf(fmaxf(acc[0], acc[1]), fmaxf(acc[2], acc[3])),
                       fmaxf(fmaxf(acc[4], acc[5]), fmaxf(acc[6], acc[7])));
      float m1 = fmaxf(fmaxf(fmaxf(acc[8], acc[9]), fmaxf(acc[10], acc[11])),
                       fmaxf(fmaxf(acc[12], acc[13]), fmaxf(acc[14], acc[15])));
      vmax[b] = fmaxf(vmax[b], fmaxf(m0, m1));
    }
    // Prefetch tile t+2 into a0 (wrap to 0 on last iter; harmless re-read).
    int t2 = t + 2;
    if (t2 > 7) t2 = 0;
#pragma unroll
    for (int k = 0; k < 8; ++k)
      a0[k] = load_a<PRECVT>(psv, pbase + t2 * 4096 + k * 16);
    // Compute tile t+1 from a1.
#pragma unroll
    for (int b = 0; b < 4; ++b) {
      floatx16 acc = {0, 0, 0, 0, 0, 0, 0, 0, 0, 0, 0, 0, 0, 0, 0, 0};
#pragma unroll
      for (int k = 0; k < 8; ++k)
        acc = __builtin_amdgcn_mfma_f32_32x32x16_bf16(a1[k], qf[b][k], acc, 0, 0, 0);
      float m0 = fmaxf(fmaxf(fmaxf(acc[0], acc[1]), fmaxf(acc[2], acc[3])),
                       fmaxf(fmaxf(acc[4], acc[5]), fmaxf(acc[6], acc[7])));
      float m1 = fmaxf(fmaxf(fmaxf(acc[8], acc[9]), fmaxf(acc[10], acc[11])),
                       fmaxf(fmaxf(acc[12], acc[13]), fmaxf(acc[14], acc[15])));
      vmax[b] = fmaxf(vmax[b], fmaxf(m0, m1));
    }
  }

  // Lanes l and l^32 hold complementary row-halves of the same query-token col.
#pragma unroll
  for (int b = 0; b < 4; ++b) vmax[b] = fmaxf(vmax[b], __shfl_xor(vmax[b], 32, 64));

  // Cross-wave max, then sum over the 32 query tokens.
  __shared__ float red[4][4][32];  // [wave][b][n]
  if (lane < 32) {
#pragma unroll
    for (int b = 0; b < 4; ++b) red[wave][b][lane] = vmax[b];
  }
  __syncthreads();
  if (threadIdx.x < 128) {
    const int b = threadIdx.x >> 5;
    const int n = threadIdx.x & 31;
    float m = fmaxf(fmaxf(red[0][b][n], red[1][b][n]), fmaxf(red[2][b][n], red[3][b][n]));
#pragma unroll
    for (int o = 16; o > 0; o >>= 1) m += __shfl_xor(m, o, 32);
    if (n == 0) out[(b0 + b) * 64 + c] = m;
  }
}

extern "C" void kernel_launch(void* const* d_in, const int* in_sizes, int n_in,
                              void* d_out, int out_size, void* d_ws, size_t ws_size,
                              hipStream_t stream) {
  const float* qs = (const float*)d_in[0];
  const float* ps = (const float*)d_in[1];
  float* out = (float*)d_out;

  const size_t need = (QS_N + PS_N) * sizeof(ushort);  // 16.5 MiB

  if (ws_size >= need) {
    ushort* wsb = (ushort*)d_ws;
    const int n4 = (int)((QS_N + PS_N) / 4);
    cvt_kernel<<<(n4 + 255) / 256, 256, 0, stream>>>(qs, ps, wsb);
    maxsim_kernel<true><<<dim3(64 * 16), dim3(256), 0, stream>>>(wsb, wsb + QS_N, out);
  } else {
    maxsim_kernel<false><<<dim3(64 * 16), dim3(256), 0, stream>>>(qs, ps, out);
  }
}